// Round 6
// baseline (558.802 us; speedup 1.0000x reference)
//
#include <hip/hip_runtime.h>
#include <hip/hip_bf16.h>

// ---------- helpers ----------
typedef __attribute__((ext_vector_type(8))) short bf16x8;
typedef __attribute__((ext_vector_type(4))) float f32x4;

static __device__ __forceinline__ short f2bf(float f) {
    unsigned u = __float_as_uint(f);
    unsigned r = (u + 0x7FFFu + ((u >> 16) & 1u)) >> 16;  // RNE
    return (short)(unsigned short)r;
}
static __device__ __forceinline__ float bf2f(short s) {
    return __uint_as_float(((unsigned)(unsigned short)s) << 16);
}
// nontemporal float4 load (keep streaming x out of L2's way)
static __device__ __forceinline__ float4 nt_load4(const float* p) {
    f32x4 v = __builtin_nontemporal_load((const f32x4*)p);
    return make_float4(v[0], v[1], v[2], v[3]);
}
// pack 8 fp32 -> bf16x8 (RNE packed cvt)
static __device__ __forceinline__ bf16x8 cvt8(const float4 lo, const float4 hi) {
    __hip_bfloat162 p0 = __float22bfloat162_rn(make_float2(lo.x, lo.y));
    __hip_bfloat162 p1 = __float22bfloat162_rn(make_float2(lo.z, lo.w));
    __hip_bfloat162 p2 = __float22bfloat162_rn(make_float2(hi.x, hi.y));
    __hip_bfloat162 p3 = __float22bfloat162_rn(make_float2(hi.z, hi.w));
    short2 s0 = *(short2*)&p0, s1 = *(short2*)&p1, s2 = *(short2*)&p2, s3 = *(short2*)&p3;
    bf16x8 r = {s0.x, s0.y, s1.x, s1.y, s2.x, s2.y, s3.x, s3.y};
    return r;
}

// ---------- degree / norm ----------
__global__ void deg_kernel(const int* __restrict__ src, const int* __restrict__ dst,
                           int* __restrict__ deg_out, int* __restrict__ deg_in, int E) {
    int e = blockIdx.x * blockDim.x + threadIdx.x;
    if (e < E) {
        atomicAdd(&deg_out[src[e]], 1);
        atomicAdd(&deg_in[dst[e]], 1);
    }
}

__global__ void norm_kernel(const int* __restrict__ deg_out, const int* __restrict__ deg_in,
                            float* __restrict__ ns, float* __restrict__ nd, int N) {
    int i = blockIdx.x * blockDim.x + threadIdx.x;
    if (i < N) {
        ns[i] = rsqrtf((float)max(deg_out[i], 1));
        nd[i] = rsqrtf((float)max(deg_in[i], 1));
    }
}

// ---------- 3-phase multi-block exclusive scan of deg_in -> offsets ----------
__global__ void scan_part1(const int* __restrict__ deg, int* __restrict__ bsum, int N) {
    __shared__ int red[256];
    int i = blockIdx.x * 256 + threadIdx.x;
    red[threadIdx.x] = (i < N) ? deg[i] : 0;
    __syncthreads();
    for (int off = 128; off > 0; off >>= 1) {
        if (threadIdx.x < off) red[threadIdx.x] += red[threadIdx.x + off];
        __syncthreads();
    }
    if (threadIdx.x == 0) bsum[blockIdx.x] = red[0];
}

__global__ void scan_part2(const int* __restrict__ bsum, int* __restrict__ bsum_ex, int NB,
                           int* __restrict__ offsets, int N, int E) {
    __shared__ int s[256];
    int t = threadIdx.x;
    int v = (t < NB) ? bsum[t] : 0;
    s[t] = v;
    __syncthreads();
    for (int off = 1; off < 256; off <<= 1) {
        int u = (t >= off) ? s[t - off] : 0;
        __syncthreads();
        s[t] += u;
        __syncthreads();
    }
    bsum_ex[t] = s[t] - v;  // exclusive
    if (t == 0) offsets[N] = E;
}

__global__ void scan_part3(const int* __restrict__ deg, const int* __restrict__ bsum_ex,
                           int* __restrict__ offsets, int N) {
    __shared__ int s[256];
    int t = threadIdx.x, i = blockIdx.x * 256 + t;
    int v = (i < N) ? deg[i] : 0;
    s[t] = v;
    __syncthreads();
    for (int off = 1; off < 256; off <<= 1) {
        int u = (t >= off) ? s[t - off] : 0;
        __syncthreads();
        s[t] += u;
        __syncthreads();
    }
    if (i < N) offsets[i] = bsum_ex[blockIdx.x] + s[t] - v;
}

// ---------- scatter edges into CSR-by-dst buckets ----------
__global__ void scatter_kernel(const int* __restrict__ src, const int* __restrict__ dst,
                               const int* __restrict__ offsets, int* __restrict__ cursor,
                               int* __restrict__ bucket, int E) {
    int e = blockIdx.x * blockDim.x + threadIdx.x;
    if (e < E) {
        int d = dst[e];
        int p = atomicAdd(&cursor[d], 1);
        bucket[offsets[d] + p] = src[e];
    }
}

// ---------- W1 [K=1024][N=256] fp32 -> Wt [n][k] bf16 ----------
__global__ __launch_bounds__(1024) void transpose_w1(const float* __restrict__ W1,
                                                     short* __restrict__ Wt) {
    __shared__ short tile[32][33];
    int k0 = blockIdx.x * 32, n0 = blockIdx.y * 32;
    int tx = threadIdx.x & 31, ty = threadIdx.x >> 5;
    tile[ty][tx] = f2bf(W1[(size_t)(k0 + ty) * 256 + (n0 + tx)]);
    __syncthreads();
    Wt[(size_t)(n0 + ty) * 1024 + (k0 + tx)] = tile[tx][ty];
}

// ---------- GEMM1: hb = bf16((x @ W1) * norm_src[row]) ----------
// Round-5 structure: BM=32, BN=256 (full D_HID -> x read ONCE, no y-dup).
// Phase 1: each x row streamed as one contiguous 4KB burst (DRAM-page friendly),
//   cvt->bf16 into 64KB LDS with XOR chunk swizzle (c ^= row&7: frag reads 2-way = free).
// Phase 2: barrier-free K-loop. A frags from LDS; B frags DIRECT from L2-resident
//   Wt (512KB, hot per-XCD), register double-buffered across k-steps.
#define BM 32
#define CSTR 264  // C-staging row stride in shorts (132 dwords == 4 mod 32 banks)

union SMem {
    short A[BM * 1024];  // 64 KB bf16, rows of 128 16B-chunks, chunk c' = c ^ (row&7)
    short C[BM * CSTR];  // 16.9 KB epilogue staging
};

__global__ __launch_bounds__(256, 2) void gemm1_kernel(const float* __restrict__ x,
                                                       const short* __restrict__ Wt,
                                                       const float* __restrict__ norm_src,
                                                       short* __restrict__ hb, int M) {
    __shared__ __align__(16) SMem sm;
    __shared__ float ns_lds[BM];
    const int tid  = threadIdx.x;
    const int lane = tid & 63;
    const int wave = tid >> 6;
    const int quad = lane >> 4;
    const int mrow = lane & 15;
    const int bm   = blockIdx.x * BM;

    if (tid < BM) ns_lds[tid] = norm_src[min(bm + tid, M - 1)];

    // ---- phase 1: wave w streams rows 8w..8w+7, 4KB contiguous each ----
    // lane covers 32B (8 k) per (row, segment); 2 segments of 2KB per row.
#pragma unroll
    for (int half = 0; half < 2; half++) {
        float4 lo[8], hi[8];
#pragma unroll
        for (int t = 0; t < 8; t++) {
            int idx = half * 8 + t;         // 0..15 = (row in 8-group) * 2 + seg
            int r   = wave * 8 + (idx >> 1);
            int s   = idx & 1;
            const float* p = x + (size_t)min(bm + r, M - 1) * 1024 + s * 512 + lane * 8;
            lo[t] = nt_load4(p);
            hi[t] = nt_load4(p + 4);
        }
#pragma unroll
        for (int t = 0; t < 8; t++) {
            int idx = half * 8 + t;
            int r   = wave * 8 + (idx >> 1);
            int s   = idx & 1;
            int c   = s * 64 + lane;        // 16B chunk index in row (0..127)
            int cs  = c ^ (r & 7);
            *(bf16x8*)((char*)sm.A + r * 2048 + cs * 16) = cvt8(lo[t], hi[t]);
        }
    }
    __syncthreads();  // A tile resident; no further barriers until epilogue

    // ---- phase 2: barrier-free K-loop ----
    f32x4 acc[2][4] = {};
    const int wn = wave * 64;
    // B frag base: lane (mrow,quad) of frag ni reads Wt[wn+ni*16+mrow][k0+quad*8 ..+8]
    const short* wB = Wt + (size_t)(wn + mrow) * 1024 + quad * 8;

    bf16x8 bA[2][2], bB[2][4];
#pragma unroll
    for (int ni = 0; ni < 4; ni++)
        bB[0][ni] = *(const bf16x8*)(wB + (size_t)ni * 16 * 1024);
#pragma unroll
    for (int mi = 0; mi < 2; mi++) {
        int r = mi * 16 + mrow;
        bA[0][mi] = *(const bf16x8*)((char*)sm.A + r * 2048 + ((quad ^ (r & 7)) * 16));
    }

    for (int k0 = 0; k0 < 1024; k0 += 32) {
        int cur = (k0 >> 5) & 1, nxt = cur ^ 1;
        if (k0 + 32 < 1024) {
            int k1 = k0 + 32;
#pragma unroll
            for (int ni = 0; ni < 4; ni++)
                bB[nxt][ni] = *(const bf16x8*)(wB + (size_t)ni * 16 * 1024 + k1);
#pragma unroll
            for (int mi = 0; mi < 2; mi++) {
                int r = mi * 16 + mrow;
                int c = (k1 >> 3) + quad;
                bA[nxt][mi] = *(const bf16x8*)((char*)sm.A + r * 2048 + ((c ^ (r & 7)) * 16));
            }
        }
#pragma unroll
        for (int mi = 0; mi < 2; mi++)
#pragma unroll
            for (int ni = 0; ni < 4; ni++)
                acc[mi][ni] = __builtin_amdgcn_mfma_f32_16x16x32_bf16(bA[cur][mi], bB[cur][ni], acc[mi][ni], 0, 0, 0);
    }

    // ---- epilogue: acc -> C LDS (scaled bf16) -> coalesced stores ----
    __syncthreads();  // A dead; reuse as C
#pragma unroll
    for (int mi = 0; mi < 2; mi++) {
#pragma unroll
        for (int reg = 0; reg < 4; reg++) {
            int row = mi * 16 + quad * 4 + reg;
            float nsv = ns_lds[row];
#pragma unroll
            for (int ni = 0; ni < 4; ni++) {
                int col = wn + ni * 16 + mrow;
                sm.C[row * CSTR + col] = f2bf(acc[mi][ni][reg] * nsv);
            }
        }
    }
    __syncthreads();
    // 32 rows x 512B: 8 threads/row, each thread 4 x 16B chunks
    {
        int row = tid >> 3;
        if (bm + row < M) {
#pragma unroll
            for (int j = 0; j < 4; j++) {
                int chunk = (tid & 7) + j * 8;  // 0..31
                int4 v = *(const int4*)&sm.C[row * CSTR + chunk * 8];
                *(int4*)(hb + (size_t)(bm + row) * 256 + chunk * 8) = v;
            }
        }
    }
}

// ---------- agg1 fused with layer-2 projection ----------
__global__ __launch_bounds__(256) void agg1_kernel(const short* __restrict__ hb,
                                                   const int* __restrict__ bucket,
                                                   const int* __restrict__ offsets,
                                                   const float* __restrict__ norm_dst,
                                                   const float* __restrict__ norm_src,
                                                   const float* __restrict__ b1,
                                                   const float* __restrict__ W2,
                                                   float* __restrict__ z, int N) {
    int wave = threadIdx.x >> 6;
    int lane = threadIdx.x & 63;
    int node = blockIdx.x * 4 + wave;
    if (node >= N) return;
    int beg = offsets[node], end = offsets[node + 1];
    float a0 = 0.f, a1 = 0.f, a2 = 0.f, a3 = 0.f;
    int e = beg;
    for (; e + 7 < end; e += 8) {  // 8 gathers in flight
        short4 v[8];
#pragma unroll
        for (int j = 0; j < 8; j++)
            v[j] = *(const short4*)(hb + (size_t)bucket[e + j] * 256 + lane * 4);
#pragma unroll
        for (int j = 0; j < 8; j++) {
            a0 += bf2f(v[j].x); a1 += bf2f(v[j].y);
            a2 += bf2f(v[j].z); a3 += bf2f(v[j].w);
        }
    }
    for (; e < end; e++) {
        short4 v0 = *(const short4*)(hb + (size_t)bucket[e] * 256 + lane * 4);
        a0 += bf2f(v0.x); a1 += bf2f(v0.y); a2 += bf2f(v0.z); a3 += bf2f(v0.w);
    }
    float nd = norm_dst[node];
    float4 bb = *(const float4*)(b1 + lane * 4);
    float o0 = fmaxf(a0 * nd + bb.x, 0.f);
    float o1 = fmaxf(a1 * nd + bb.y, 0.f);
    float o2 = fmaxf(a2 * nd + bb.z, 0.f);
    float o3 = fmaxf(a3 * nd + bb.w, 0.f);
    float4 w = *(const float4*)(W2 + lane * 4);
    float p = o0 * w.x + o1 * w.y + o2 * w.z + o3 * w.w;
#pragma unroll
    for (int off = 32; off > 0; off >>= 1) p += __shfl_xor(p, off, 64);
    if (lane == 0) z[node] = p * norm_src[node];
}

// ---------- agg2: out = relu(norm_dst * sum z[src] + b2) ----------
__global__ void agg2_kernel(const float* __restrict__ z, const int* __restrict__ bucket,
                            const int* __restrict__ offsets, const float* __restrict__ norm_dst,
                            const float* __restrict__ b2, float* __restrict__ out, int N) {
    int i = blockIdx.x * blockDim.x + threadIdx.x;
    if (i >= N) return;
    int beg = offsets[i], end = offsets[i + 1];
    float s = 0.f;
    for (int e = beg; e < end; e++) s += z[bucket[e]];
    out[i] = fmaxf(s * norm_dst[i] + b2[0], 0.f);
}

extern "C" void kernel_launch(void* const* d_in, const int* in_sizes, int n_in,
                              void* d_out, int out_size, void* d_ws, size_t ws_size,
                              hipStream_t stream) {
    const int D_HID = in_sizes[4];           // 256
    const int D_IN  = in_sizes[3] / D_HID;   // 1024
    const int N     = in_sizes[0] / D_IN;    // 50000
    const int E     = in_sizes[1];           // 800000

    const float* x   = (const float*)d_in[0];
    const int*   src = (const int*)d_in[1];
    const int*   dst = (const int*)d_in[2];
    const float* W1  = (const float*)d_in[3];
    const float* b1  = (const float*)d_in[4];
    const float* W2  = (const float*)d_in[5];
    const float* b2  = (const float*)d_in[6];
    float* out = (float*)d_out;

    char* p = (char*)d_ws;
    auto alloc = [&](size_t bytes) {
        void* r = (void*)p;
        p += (bytes + 255) & ~(size_t)255;
        return r;
    };
    int*   deg_out  = (int*)alloc((size_t)N * 4);
    int*   deg_in   = (int*)alloc((size_t)N * 4);
    int*   cursor   = (int*)alloc((size_t)N * 4);
    float* norm_src = (float*)alloc((size_t)N * 4);
    float* norm_dst = (float*)alloc((size_t)N * 4);
    int*   offsets  = (int*)alloc((size_t)(N + 1) * 4);
    int*   bucket   = (int*)alloc((size_t)E * 4);
    short* Wt       = (short*)alloc((size_t)D_IN * D_HID * 2);
    short* hb       = (short*)alloc((size_t)N * D_HID * 2);
    float* z        = (float*)alloc((size_t)N * 4);
    int*   bsum     = (int*)alloc(256 * 4);
    int*   bsum_ex  = (int*)alloc(256 * 4);

    const int NB = (N + 255) / 256;  // 196 scan blocks

    (void)hipMemsetAsync(deg_out, 0, (size_t)N * 4, stream);
    (void)hipMemsetAsync(deg_in,  0, (size_t)N * 4, stream);
    (void)hipMemsetAsync(cursor,  0, (size_t)N * 4, stream);

    deg_kernel<<<(E + 255) / 256, 256, 0, stream>>>(src, dst, deg_out, deg_in, E);
    norm_kernel<<<(N + 255) / 256, 256, 0, stream>>>(deg_out, deg_in, norm_src, norm_dst, N);
    scan_part1<<<NB, 256, 0, stream>>>(deg_in, bsum, N);
    scan_part2<<<1, 256, 0, stream>>>(bsum, bsum_ex, NB, offsets, N, E);
    scan_part3<<<NB, 256, 0, stream>>>(deg_in, bsum_ex, offsets, N);
    scatter_kernel<<<(E + 255) / 256, 256, 0, stream>>>(src, dst, offsets, cursor, bucket, E);
    transpose_w1<<<dim3(D_IN / 32, D_HID / 32), 1024, 0, stream>>>(W1, Wt);
    gemm1_kernel<<<(N + BM - 1) / BM, 256, 0, stream>>>(x, Wt, norm_src, hb, N);
    agg1_kernel<<<(N + 3) / 4, 256, 0, stream>>>(hb, bucket, offsets, norm_dst, norm_src, b1, W2, z, N);
    agg2_kernel<<<(N + 255) / 256, 256, 0, stream>>>(z, bucket, offsets, norm_dst, b2, out, N);
}